// Round 5
// baseline (577.803 us; speedup 1.0000x reference)
//
#include <hip/hip_runtime.h>

#define N_NODES 100000
#define N_EDGES 1600000
#define NB 391          // coarse buckets of 256 nodes
#define BCAP 5120       // per-bucket capacity (expected 4096, 16-sigma headroom)
#define PART_BLOCKS 250
#define EPB 6400        // edges per partition block (250*6400 = 1.6M exact)

// Column-group tiling: feature dims split into 8 groups, group g pinned to XCD g
// (blockIdx & 7). Per-XCD gather footprint: 100000*16*2B = 3.2 MB < 4 MiB L2.
#define SL1 ((size_t)N_NODES * 16)   // bf16 elements per group slice (layer 1: 16 cols)
#define SL2 ((size_t)N_NODES * 8)    // f32 elements per group slice (layer 2: 8 cols)

typedef __attribute__((ext_vector_type(8))) short short8;   // 8 bf16 (4 VGPR) MFMA frag
typedef __attribute__((ext_vector_type(4))) float f32x4;    // MFMA accumulator

__device__ inline unsigned short f2bf(float f) {
    unsigned int u = __builtin_bit_cast(unsigned int, f);
    u += 0x7fffu + ((u >> 16) & 1u);   // round-to-nearest-even
    return (unsigned short)(u >> 16);
}
__device__ inline float bf2f(unsigned short h) {
    unsigned int u = ((unsigned int)h) << 16;
    return __builtin_bit_cast(float, u);
}

// ---- xbt[g][node][16] = bf16(x * out_norm[row]), column-group tiled ----
__global__ __launch_bounds__(256) void k_xb(const float* __restrict__ x, const float* __restrict__ out_norm,
                                            unsigned short* __restrict__ xbt) {
    int tid = blockIdx.x * 256 + threadIdx.x;   // grid exactly N*32
    int row = tid >> 5, t = tid & 31;           // t: which float4 (cols 4t..4t+3)
    float4 v = ((const float4*)x)[tid];
    float w = out_norm[row];
    unsigned int lo = (unsigned int)f2bf(v.x * w) | ((unsigned int)f2bf(v.y * w) << 16);
    unsigned int hi = (unsigned int)f2bf(v.z * w) | ((unsigned int)f2bf(v.w * w) << 16);
    int g = t >> 2, c4 = (t & 3) * 4;
    *(uint2*)(xbt + (size_t)g * SL1 + (size_t)row * 16 + c4) = make_uint2(lo, hi);
}

// ---- pack W1/W2 (f32) into bf16 B-fragment layout: entry (kq, c) = W[kq*8+j][c], j=0..7 ----
__global__ __launch_bounds__(256) void k_pack_w(const float* __restrict__ W1, const float* __restrict__ W2,
                                                unsigned short* __restrict__ Wp1, unsigned short* __restrict__ Wp2) {
    int i = blockIdx.x * 256 + threadIdx.x;   // 3072 total
    if (i < 2048) {                           // W1: 16 kq x 128 c
        int kq = i >> 7, c = i & 127;
#pragma unroll
        for (int j = 0; j < 8; j++) Wp1[i * 8 + j] = f2bf(W1[(kq * 8 + j) * 128 + c]);
    } else if (i < 3072) {                    // W2: 16 kq x 64 c
        int i2 = i - 2048;
        int kq = i2 >> 6, c = i2 & 63;
#pragma unroll
        for (int j = 0; j < 8; j++) Wp2[i2 * 8 + j] = f2bf(W2[(kq * 8 + j) * 64 + c]);
    }
}

// ---- partition: dst-keyed buckets (full edge) + src-keyed buckets (1 byte) ----
__global__ __launch_bounds__(256) void k_part(const int* __restrict__ src, const int* __restrict__ dst,
                                              int* __restrict__ gcurD, int* __restrict__ gcurS,
                                              unsigned int* __restrict__ ebuf,
                                              unsigned char* __restrict__ ebufS) {
    __shared__ int histD[NB], gbaseD[NB];
    __shared__ int histS[NB], gbaseS[NB];
    for (int i = threadIdx.x; i < NB; i += 256) { histD[i] = 0; histS[i] = 0; }
    __syncthreads();
    int base = blockIdx.x * EPB;
    for (int i = threadIdx.x; i < EPB; i += 256) {
        int d = dst[base + i], s = src[base + i];
        atomicAdd(&histD[d >> 8], 1);
        atomicAdd(&histS[s >> 8], 1);
    }
    __syncthreads();
    for (int i = threadIdx.x; i < NB; i += 256) {
        gbaseD[i] = atomicAdd(&gcurD[i], histD[i]);
        gbaseS[i] = atomicAdd(&gcurS[i], histS[i]);
        histD[i] = 0;                          // reuse as local run cursors
        histS[i] = 0;
    }
    __syncthreads();
    for (int i = threadIdx.x; i < EPB; i += 256) {
        int d = dst[base + i], s = src[base + i];
        int bd = d >> 8;
        int r = atomicAdd(&histD[bd], 1);
        int pos = gbaseD[bd] + r;
        if (pos < BCAP) ebuf[(size_t)bd * BCAP + pos] = ((unsigned int)s << 8) | (unsigned int)(d & 255);
        int bs = s >> 8;
        int r2 = atomicAdd(&histS[bs], 1);
        int pos2 = gbaseS[bs] + r2;
        if (pos2 < BCAP) ebufS[(size_t)bs * BCAP + pos2] = (unsigned char)(s & 255);
    }
}

// ---- per-bucket out-degree histogram -> out_norm ----
__global__ __launch_bounds__(256) void k_bhist(const unsigned char* __restrict__ ebufS,
                                               const int* __restrict__ gcurS,
                                               float* __restrict__ out_norm) {
    __shared__ int hist[256];
    int b = blockIdx.x, t = threadIdx.x;
    hist[t] = 0;
    __syncthreads();
    int ne = min(gcurS[b], BCAP);
    const unsigned char* eb = ebufS + (size_t)b * BCAP;
    for (int i = t; i < ne; i += 256) atomicAdd(&hist[eb[i]], 1);
    __syncthreads();
    int node = b * 256 + t;
    if (node < N_NODES) out_norm[node] = hist[t] > 0 ? rsqrtf((float)hist[t]) : 1.0f;
}

// ---- exclusive scan of dst-bucket counts -> bucket bases; row_ptr[N] = E ----
__global__ __launch_bounds__(512) void k_bscan(const int* __restrict__ gcurD, int* __restrict__ bbase,
                                               int* __restrict__ row_ptr) {
    __shared__ int s[NB + 1];
    int t = threadIdx.x;
    if (t < NB) s[t] = min(gcurD[t], BCAP);
    __syncthreads();
    if (t == 0) {
        int run = 0;
        for (int b = 0; b < NB; b++) { int v = s[b]; s[b] = run; run += v; }
        s[NB] = run;
    }
    __syncthreads();
    if (t < NB) bbase[t] = s[t];
    if (t == 0) { bbase[NB] = s[NB]; row_ptr[N_NODES] = s[NB]; }
}

// ---- per-bucket counting sort in LDS: emits coalesced csr_src, row_ptr, in_norm ----
__global__ __launch_bounds__(256) void k_bsort(const unsigned int* __restrict__ ebuf, const int* __restrict__ gcurD,
                                               const int* __restrict__ bbase, int* __restrict__ csr_src,
                                               int* __restrict__ row_ptr, float* __restrict__ in_norm) {
    __shared__ unsigned int st[BCAP];   // 20 KB staged edges
    __shared__ int perm[BCAP];          // 20 KB sorted srcs
    __shared__ int hist[256], cursor[256], sa[256], sb[256];
    int b = blockIdx.x, t = threadIdx.x;
    int ne = min(gcurD[b], BCAP);
    const unsigned int* eb = ebuf + (size_t)b * BCAP;
    hist[t] = 0;
    __syncthreads();
    for (int i = t; i < ne; i += 256) {
        unsigned int pk = eb[i];
        st[i] = pk;
        atomicAdd(&hist[pk & 255u], 1);
    }
    __syncthreads();
    sa[t] = hist[t];
    __syncthreads();
    int* cur = sa; int* nxt = sb;
    for (int o = 1; o < 256; o <<= 1) {
        int v = cur[t] + (t >= o ? cur[t - o] : 0);
        nxt[t] = v;
        __syncthreads();
        int* tmp = cur; cur = nxt; nxt = tmp;
    }
    int ex = cur[t] - hist[t];   // exclusive
    cursor[t] = ex;
    int node = b * 256 + t;
    if (node < N_NODES) {
        row_ptr[node] = bbase[b] + ex;
        in_norm[node] = hist[t] > 0 ? rsqrtf((float)hist[t]) : 1.0f;
    }
    __syncthreads();
    for (int i = t; i < ne; i += 256) {
        unsigned int pk = st[i];
        int pos = atomicAdd(&cursor[pk & 255u], 1);
        perm[pos] = (int)(pk >> 8);
    }
    __syncthreads();
    int gb = bbase[b];
    for (int i = t; i < ne; i += 256) csr_src[gb + i] = perm[i];
}

// ---- layer-1 aggregation, XCD-pinned column groups ----
// Group g = blockIdx&7 (one XCD): 16 bf16 cols, slice = 3.2 MB (L2-resident).
// 8 lanes/edge x 8 edge slots, 2-deep unroll = 16 edges in flight per wave.
// Butterfly shfl_xor(8,16,32) reduces edge slots; lanes 0..7 write 32B/node.
__global__ __launch_bounds__(256) void k_agg1(const unsigned short* __restrict__ xbt,
                                              const int* __restrict__ row_ptr, const int* __restrict__ csr,
                                              const float* __restrict__ in_norm,
                                              unsigned short* __restrict__ agg1t) {
    int gid = blockIdx.x & 7;
    int chunk = blockIdx.x >> 3;                 // 6250 chunks of 16 nodes
    int wave = threadIdx.x >> 6, lane = threadIdx.x & 63;
    int grp8 = lane >> 3, li = lane & 7;         // edge slot / col pair
    const unsigned short* xg = xbt + (size_t)gid * SL1;
    unsigned short* og = agg1t + (size_t)gid * SL1;
#pragma unroll
    for (int nd = 0; nd < 4; nd++) {
        int d = chunk * 16 + wave * 4 + nd;
        if (d >= N_NODES) break;
        int e0 = __builtin_amdgcn_readfirstlane(row_ptr[d]);
        int e1 = __builtin_amdgcn_readfirstlane(row_ptr[d + 1]);
        float l0 = 0.f, h0 = 0.f, l1 = 0.f, h1 = 0.f;
        int e = e0;
        for (; e + 16 <= e1; e += 16) {
            int sA = csr[e + grp8];
            int sB = csr[e + 8 + grp8];
            unsigned int vA = *(const unsigned int*)(xg + (size_t)sA * 16 + 2 * li);
            unsigned int vB = *(const unsigned int*)(xg + (size_t)sB * 16 + 2 * li);
            l0 += bf2f((unsigned short)(vA & 0xffffu)); h0 += bf2f((unsigned short)(vA >> 16));
            l1 += bf2f((unsigned short)(vB & 0xffffu)); h1 += bf2f((unsigned short)(vB >> 16));
        }
        for (; e < e1; e += 8) {
            unsigned int v = 0;
            if (e + grp8 < e1) {
                int s = csr[e + grp8];
                v = *(const unsigned int*)(xg + (size_t)s * 16 + 2 * li);
            }
            l0 += bf2f((unsigned short)(v & 0xffffu)); h0 += bf2f((unsigned short)(v >> 16));
        }
        float a0 = l0 + l1, a1 = h0 + h1;
#pragma unroll
        for (int o = 8; o < 64; o <<= 1) { a0 += __shfl_xor(a0, o); a1 += __shfl_xor(a1, o); }
        float w = in_norm[d];
        if (grp8 == 0) {
            unsigned int pk = (unsigned int)f2bf(a0 * w) | ((unsigned int)f2bf(a1 * w) << 16);
            *(unsigned int*)(og + (size_t)d * 16 + 2 * li) = pk;
        }
    }
}

// ---- GEMM1: z = relu(agg1t @ W1 + b1); zs = bf16(z * out_norm). A read from tiled layout ----
__global__ __launch_bounds__(256) void k_gemm1(const unsigned short* __restrict__ agg1t,
                                               const unsigned short* __restrict__ Wp,
                                               const float* __restrict__ bias,
                                               const float* __restrict__ out_norm,
                                               float* __restrict__ z_out,
                                               unsigned short* __restrict__ zs) {
    __shared__ __align__(16) unsigned short lds[16 * 128 * 8];   // 32 KB packed W1
    {
        const uint4* s4 = (const uint4*)Wp; uint4* d4 = (uint4*)lds;
        for (int i = threadIdx.x; i < 2048; i += 256) d4[i] = s4[i];
    }
    __syncthreads();
    int wave = threadIdx.x >> 6, lane = threadIdx.x & 63;
    int base = (blockIdx.x * 4 + wave) * 16;
    if (base >= N_NODES) return;
    int m = lane & 15, q = lane >> 4;
    short8 a[4];
#pragma unroll
    for (int t = 0; t < 4; t++) {   // cols t*32+q*8..+8 -> group 2t+(q>>1), offset (q&1)*8
        const unsigned short* ag = agg1t + (size_t)(2 * t + (q >> 1)) * SL1;
        a[t] = *(const short8*)(ag + (size_t)(base + m) * 16 + (q & 1) * 8);
    }
    f32x4 acc[8];
#pragma unroll
    for (int c = 0; c < 8; c++) acc[c] = (f32x4)(0.f);
#pragma unroll
    for (int ct = 0; ct < 8; ct++) {
#pragma unroll
        for (int t = 0; t < 4; t++) {
            short8 b = *(const short8*)(lds + ((t * 4 + q) * 128 + ct * 16 + m) * 8);
            acc[ct] = __builtin_amdgcn_mfma_f32_16x16x32_bf16(a[t], b, acc[ct], 0, 0, 0);
        }
    }
    float onr[4];
#pragma unroll
    for (int i = 0; i < 4; i++) onr[i] = out_norm[base + q * 4 + i];
#pragma unroll
    for (int ct = 0; ct < 8; ct++) {
        int col = ct * 16 + m;
        float bv = bias[col];
#pragma unroll
        for (int i = 0; i < 4; i++) {
            int row = base + q * 4 + i;
            float v = acc[ct][i] + bv;
            v = v > 0.f ? v : 0.f;
            z_out[(size_t)row * 128 + col] = v;
            zs[(size_t)row * 128 + col] = f2bf(v * onr[i]);
        }
    }
}

// ---- GEMM2: tbt[g][node][8] = zs @ W2 (column-group tiled f32 out) ----
__global__ __launch_bounds__(256) void k_gemm2(const unsigned short* __restrict__ Ab,
                                               const unsigned short* __restrict__ Wp,
                                               float* __restrict__ tbt) {
    __shared__ __align__(16) unsigned short lds[16 * 64 * 8];   // 16 KB packed W2
    {
        const uint4* s4 = (const uint4*)Wp; uint4* d4 = (uint4*)lds;
        for (int i = threadIdx.x; i < 1024; i += 256) d4[i] = s4[i];
    }
    __syncthreads();
    int wave = threadIdx.x >> 6, lane = threadIdx.x & 63;
    int base = (blockIdx.x * 4 + wave) * 16;
    if (base >= N_NODES) return;
    int m = lane & 15, q = lane >> 4;
    short8 a[4];
#pragma unroll
    for (int t = 0; t < 4; t++) a[t] = *(const short8*)(Ab + (size_t)(base + m) * 128 + t * 32 + q * 8);
    f32x4 acc[4];
#pragma unroll
    for (int c = 0; c < 4; c++) acc[c] = (f32x4)(0.f);
#pragma unroll
    for (int ct = 0; ct < 4; ct++) {
#pragma unroll
        for (int t = 0; t < 4; t++) {
            short8 b = *(const short8*)(lds + ((t * 4 + q) * 64 + ct * 16 + m) * 8);
            acc[ct] = __builtin_amdgcn_mfma_f32_16x16x32_bf16(a[t], b, acc[ct], 0, 0, 0);
        }
    }
#pragma unroll
    for (int ct = 0; ct < 4; ct++) {
        int col = ct * 16 + m;
        int g = col >> 3, c = col & 7;
#pragma unroll
        for (int i = 0; i < 4; i++) {
            int row = base + q * 4 + i;
            tbt[(size_t)g * SL2 + (size_t)row * 8 + c] = acc[ct][i];
        }
    }
}

// ---- layer-2 aggregation, XCD-pinned column groups (8 f32 cols, 3.2 MB slice) ----
__global__ __launch_bounds__(256) void k_agg2(const float* __restrict__ tbt,
                                              const int* __restrict__ row_ptr, const int* __restrict__ csr,
                                              const float* __restrict__ in_norm, const float* __restrict__ b2,
                                              float* __restrict__ out_h2) {
    int gid = blockIdx.x & 7;
    int chunk = blockIdx.x >> 3;
    int wave = threadIdx.x >> 6, lane = threadIdx.x & 63;
    int grp8 = lane >> 3, li = lane & 7;
    const float* tg = tbt + (size_t)gid * SL2;
    float bv = b2[gid * 8 + li];
#pragma unroll
    for (int nd = 0; nd < 4; nd++) {
        int d = chunk * 16 + wave * 4 + nd;
        if (d >= N_NODES) break;
        int e0 = __builtin_amdgcn_readfirstlane(row_ptr[d]);
        int e1 = __builtin_amdgcn_readfirstlane(row_ptr[d + 1]);
        float a0 = 0.f, a1 = 0.f;
        int e = e0;
        for (; e + 16 <= e1; e += 16) {
            int sA = csr[e + grp8];
            int sB = csr[e + 8 + grp8];
            a0 += tg[(size_t)sA * 8 + li];
            a1 += tg[(size_t)sB * 8 + li];
        }
        for (; e < e1; e += 8) {
            float v = 0.f;
            if (e + grp8 < e1) {
                int s = csr[e + grp8];
                v = tg[(size_t)s * 8 + li];
            }
            a0 += v;
        }
        float a = a0 + a1;
#pragma unroll
        for (int o = 8; o < 64; o <<= 1) a += __shfl_xor(a, o);
        float w = in_norm[d];
        if (grp8 == 0) out_h2[(size_t)d * 64 + gid * 8 + li] = a * w + bv;
    }
}

extern "C" void kernel_launch(void* const* d_in, const int* in_sizes, int n_in,
                              void* d_out, int out_size, void* d_ws, size_t ws_size,
                              hipStream_t stream) {
    const float* x   = (const float*)d_in[0];
    const int*   src = (const int*)d_in[1];
    const int*   dst = (const int*)d_in[2];
    const float* W1  = (const float*)d_in[3];
    const float* b1  = (const float*)d_in[4];
    const float* W2  = (const float*)d_in[5];
    const float* b2  = (const float*)d_in[6];
    float* out_h2 = (float*)d_out;                     // [N,64]
    float* out_z  = (float*)d_out + N_NODES * 64;      // [N,128]

    char* ws = (char*)d_ws;
    size_t off = 0;
    auto alloc = [&](size_t bytes) -> char* {
        char* p = ws + off;
        off = (off + bytes + 255) & ~(size_t)255;
        return p;
    };
    int* gcurD    = (int*)alloc(NB * 4);
    int* gcurS    = (int*)alloc(NB * 4);
    int* bbase    = (int*)alloc((NB + 1) * 4);
    int* row_ptr  = (int*)alloc((N_NODES + 1) * 4);
    float* out_norm = (float*)alloc(N_NODES * 4);
    float* in_norm  = (float*)alloc(N_NODES * 4);
    unsigned int* ebuf = (unsigned int*)alloc((size_t)NB * BCAP * 4);        // 8.0 MB
    unsigned char* ebufS = (unsigned char*)alloc((size_t)NB * BCAP);         // 2.0 MB
    int* csr_src  = (int*)alloc((size_t)N_EDGES * 4);
    unsigned short* Wp1 = (unsigned short*)alloc(2048 * 8 * 2);
    unsigned short* Wp2 = (unsigned short*)alloc(1024 * 8 * 2);
    unsigned short* xbt   = (unsigned short*)alloc((size_t)N_NODES * 128 * 2);  // [8][N][16]
    unsigned short* agg1t = (unsigned short*)alloc((size_t)N_NODES * 128 * 2);  // [8][N][16]
    unsigned short* zs    = (unsigned short*)alloc((size_t)N_NODES * 128 * 2);  // [N][128]
    float* tbt = (float*)alloc((size_t)N_NODES * 64 * 4);                       // [8][N][8]
    (void)ws_size; (void)in_sizes; (void)n_in; (void)out_size;

    hipMemsetAsync(gcurD, 0, NB * 4, stream);
    hipMemsetAsync(gcurS, 0, NB * 4, stream);

    const int GD_AGG = 8 * ((N_NODES + 15) / 16);   // 50000: 8 groups x 6250 chunks
    const int GD_GEMM = (N_NODES / 16 + 3) / 4;     // 1563

    k_part<<<PART_BLOCKS, 256, 0, stream>>>(src, dst, gcurD, gcurS, ebuf, ebufS);
    k_bhist<<<NB, 256, 0, stream>>>(ebufS, gcurS, out_norm);
    k_bscan<<<1, 512, 0, stream>>>(gcurD, bbase, row_ptr);
    k_bsort<<<NB, 256, 0, stream>>>(ebuf, gcurD, bbase, csr_src, row_ptr, in_norm);
    k_xb<<<N_NODES * 32 / 256, 256, 0, stream>>>(x, out_norm, xbt);
    k_pack_w<<<12, 256, 0, stream>>>(W1, W2, Wp1, Wp2);
    k_agg1<<<GD_AGG, 256, 0, stream>>>(xbt, row_ptr, csr_src, in_norm, agg1t);
    k_gemm1<<<GD_GEMM, 256, 0, stream>>>(agg1t, Wp1, b1, out_norm, out_z, zs);
    k_gemm2<<<GD_GEMM, 256, 0, stream>>>(zs, Wp2, tbt);
    k_agg2<<<GD_AGG, 256, 0, stream>>>(tbt, row_ptr, csr_src, in_norm, b2, out_h2);
}

// Round 6
// 337.660 us; speedup vs baseline: 1.7112x; 1.7112x over previous
//
#include <hip/hip_runtime.h>

#define N_NODES 100000
#define N_EDGES 1600000
#define NB 391          // coarse buckets of 256 nodes
#define BCAP 5120       // per-bucket capacity (expected 4096, 16-sigma headroom)
#define PART_BLOCKS 250
#define EPB 6400        // edges per partition block (250*6400 = 1.6M exact)

typedef __attribute__((ext_vector_type(8))) short short8;   // 8 bf16 (4 VGPR) MFMA frag
typedef __attribute__((ext_vector_type(4))) float f32x4;    // MFMA accumulator

__device__ inline unsigned short f2bf(float f) {
    unsigned int u = __builtin_bit_cast(unsigned int, f);
    u += 0x7fffu + ((u >> 16) & 1u);   // round-to-nearest-even
    return (unsigned short)(u >> 16);
}
__device__ inline float bf2f(unsigned short h) {
    unsigned int u = ((unsigned int)h) << 16;
    return __builtin_bit_cast(float, u);
}

// ---- xb = bf16(x * out_norm[row]) ----
__global__ __launch_bounds__(256) void k_xb(const float* __restrict__ x, const float* __restrict__ out_norm,
                                            unsigned short* __restrict__ xb) {
    int tid = blockIdx.x * 256 + threadIdx.x;   // grid exactly N*32
    int row = tid >> 5;
    float4 v = ((const float4*)x)[tid];
    float w = out_norm[row];
    unsigned int lo = (unsigned int)f2bf(v.x * w) | ((unsigned int)f2bf(v.y * w) << 16);
    unsigned int hi = (unsigned int)f2bf(v.z * w) | ((unsigned int)f2bf(v.w * w) << 16);
    ((uint2*)xb)[tid] = make_uint2(lo, hi);
}

// ---- pack W1/W2 (f32) into bf16 B-fragment layout: entry (kq, c) = W[kq*8+j][c], j=0..7 ----
__global__ __launch_bounds__(256) void k_pack_w(const float* __restrict__ W1, const float* __restrict__ W2,
                                                unsigned short* __restrict__ Wp1, unsigned short* __restrict__ Wp2) {
    int i = blockIdx.x * 256 + threadIdx.x;   // 3072 total
    if (i < 2048) {                           // W1: 16 kq x 128 c
        int kq = i >> 7, c = i & 127;
#pragma unroll
        for (int j = 0; j < 8; j++) Wp1[i * 8 + j] = f2bf(W1[(kq * 8 + j) * 128 + c]);
    } else if (i < 3072) {                    // W2: 16 kq x 64 c
        int i2 = i - 2048;
        int kq = i2 >> 6, c = i2 & 63;
#pragma unroll
        for (int j = 0; j < 8; j++) Wp2[i2 * 8 + j] = f2bf(W2[(kq * 8 + j) * 64 + c]);
    }
}

// ---- partition: dst-keyed buckets (full edge) + src-keyed buckets (1 byte) ----
__global__ __launch_bounds__(256) void k_part(const int* __restrict__ src, const int* __restrict__ dst,
                                              int* __restrict__ gcurD, int* __restrict__ gcurS,
                                              unsigned int* __restrict__ ebuf,
                                              unsigned char* __restrict__ ebufS) {
    __shared__ int histD[NB], gbaseD[NB];
    __shared__ int histS[NB], gbaseS[NB];
    for (int i = threadIdx.x; i < NB; i += 256) { histD[i] = 0; histS[i] = 0; }
    __syncthreads();
    int base = blockIdx.x * EPB;
    for (int i = threadIdx.x; i < EPB; i += 256) {
        int d = dst[base + i], s = src[base + i];
        atomicAdd(&histD[d >> 8], 1);
        atomicAdd(&histS[s >> 8], 1);
    }
    __syncthreads();
    for (int i = threadIdx.x; i < NB; i += 256) {
        gbaseD[i] = atomicAdd(&gcurD[i], histD[i]);
        gbaseS[i] = atomicAdd(&gcurS[i], histS[i]);
        histD[i] = 0;                          // reuse as local run cursors
        histS[i] = 0;
    }
    __syncthreads();
    for (int i = threadIdx.x; i < EPB; i += 256) {
        int d = dst[base + i], s = src[base + i];
        int bd = d >> 8;
        int r = atomicAdd(&histD[bd], 1);
        int pos = gbaseD[bd] + r;
        if (pos < BCAP) ebuf[(size_t)bd * BCAP + pos] = ((unsigned int)s << 8) | (unsigned int)(d & 255);
        int bs = s >> 8;
        int r2 = atomicAdd(&histS[bs], 1);
        int pos2 = gbaseS[bs] + r2;
        if (pos2 < BCAP) ebufS[(size_t)bs * BCAP + pos2] = (unsigned char)(s & 255);
    }
}

// ---- per-bucket out-degree histogram -> out_norm ----
__global__ __launch_bounds__(256) void k_bhist(const unsigned char* __restrict__ ebufS,
                                               const int* __restrict__ gcurS,
                                               float* __restrict__ out_norm) {
    __shared__ int hist[256];
    int b = blockIdx.x, t = threadIdx.x;
    hist[t] = 0;
    __syncthreads();
    int ne = min(gcurS[b], BCAP);
    const unsigned char* eb = ebufS + (size_t)b * BCAP;
    for (int i = t; i < ne; i += 256) atomicAdd(&hist[eb[i]], 1);
    __syncthreads();
    int node = b * 256 + t;
    if (node < N_NODES) out_norm[node] = hist[t] > 0 ? rsqrtf((float)hist[t]) : 1.0f;
}

// ---- exclusive scan of dst-bucket counts -> bucket bases; row_ptr[N] = E ----
__global__ __launch_bounds__(512) void k_bscan(const int* __restrict__ gcurD, int* __restrict__ bbase,
                                               int* __restrict__ row_ptr) {
    __shared__ int s[NB + 1];
    int t = threadIdx.x;
    if (t < NB) s[t] = min(gcurD[t], BCAP);
    __syncthreads();
    if (t == 0) {
        int run = 0;
        for (int b = 0; b < NB; b++) { int v = s[b]; s[b] = run; run += v; }
        s[NB] = run;
    }
    __syncthreads();
    if (t < NB) bbase[t] = s[t];
    if (t == 0) { bbase[NB] = s[NB]; row_ptr[N_NODES] = s[NB]; }
}

// ---- per-bucket counting sort in LDS: emits coalesced csr_src, row_ptr, in_norm ----
__global__ __launch_bounds__(256) void k_bsort(const unsigned int* __restrict__ ebuf, const int* __restrict__ gcurD,
                                               const int* __restrict__ bbase, int* __restrict__ csr_src,
                                               int* __restrict__ row_ptr, float* __restrict__ in_norm) {
    __shared__ unsigned int st[BCAP];   // 20 KB staged edges
    __shared__ int perm[BCAP];          // 20 KB sorted srcs
    __shared__ int hist[256], cursor[256], sa[256], sb[256];
    int b = blockIdx.x, t = threadIdx.x;
    int ne = min(gcurD[b], BCAP);
    const unsigned int* eb = ebuf + (size_t)b * BCAP;
    hist[t] = 0;
    __syncthreads();
    for (int i = t; i < ne; i += 256) {
        unsigned int pk = eb[i];
        st[i] = pk;
        atomicAdd(&hist[pk & 255u], 1);
    }
    __syncthreads();
    sa[t] = hist[t];
    __syncthreads();
    int* cur = sa; int* nxt = sb;
    for (int o = 1; o < 256; o <<= 1) {
        int v = cur[t] + (t >= o ? cur[t - o] : 0);
        nxt[t] = v;
        __syncthreads();
        int* tmp = cur; cur = nxt; nxt = tmp;
    }
    int ex = cur[t] - hist[t];   // exclusive
    cursor[t] = ex;
    int node = b * 256 + t;
    if (node < N_NODES) {
        row_ptr[node] = bbase[b] + ex;
        in_norm[node] = hist[t] > 0 ? rsqrtf((float)hist[t]) : 1.0f;
    }
    __syncthreads();
    for (int i = t; i < ne; i += 256) {
        unsigned int pk = st[i];
        int pos = atomicAdd(&cursor[pk & 255u], 1);
        perm[pos] = (int)(pk >> 8);
    }
    __syncthreads();
    int gb = bbase[b];
    for (int i = t; i < ne; i += 256) csr_src[gb + i] = perm[i];
}

// ---- layer-1 aggregation: wave per dst node, 128 bf16 cols (2/lane), f32 accum ----
// 8-deep unrolled gather; 256 B contiguous per edge-instruction (R5 lesson:
// never trade contiguity for L2 pinning — 8x32B scattered was 3x slower).
__global__ __launch_bounds__(256) void k_agg1(const unsigned short* __restrict__ xb,
                                              const int* __restrict__ row_ptr, const int* __restrict__ csr,
                                              const float* __restrict__ in_norm,
                                              unsigned short* __restrict__ aggb) {
    int wave = threadIdx.x >> 6, lane = threadIdx.x & 63;
    int d = blockIdx.x * 4 + wave;
    if (d >= N_NODES) return;
    int e0 = __builtin_amdgcn_readfirstlane(row_ptr[d]);
    int e1 = __builtin_amdgcn_readfirstlane(row_ptr[d + 1]);
    int col = lane << 1;
    float accL[8], accH[8];
#pragma unroll
    for (int j = 0; j < 8; j++) { accL[j] = 0.f; accH[j] = 0.f; }
    int e = e0;
    for (; e + 8 <= e1; e += 8) {
        int sI[8];
#pragma unroll
        for (int j = 0; j < 8; j++) sI[j] = __builtin_amdgcn_readfirstlane(csr[e + j]);
        unsigned int v[8];
#pragma unroll
        for (int j = 0; j < 8; j++) v[j] = *(const unsigned int*)(xb + (size_t)sI[j] * 128 + col);
#pragma unroll
        for (int j = 0; j < 8; j++) {
            accL[j] += bf2f((unsigned short)(v[j] & 0xffffu));
            accH[j] += bf2f((unsigned short)(v[j] >> 16));
        }
    }
    for (; e < e1; e++) {
        int s = __builtin_amdgcn_readfirstlane(csr[e]);
        unsigned int v = *(const unsigned int*)(xb + (size_t)s * 128 + col);
        accL[0] += bf2f((unsigned short)(v & 0xffffu));
        accH[0] += bf2f((unsigned short)(v >> 16));
    }
    float a0 = 0.f, a1 = 0.f;
#pragma unroll
    for (int j = 0; j < 8; j++) { a0 += accL[j]; a1 += accH[j]; }
    float w = in_norm[d];
    unsigned int pk = (unsigned int)f2bf(a0 * w) | ((unsigned int)f2bf(a1 * w) << 16);
    *(unsigned int*)(aggb + (size_t)d * 128 + col) = pk;
}

// ---- GEMM1: z = relu(agg1b @ W1 + b1); zs = bf16(z * out_norm) ----
__global__ __launch_bounds__(256) void k_gemm1(const unsigned short* __restrict__ Ab,
                                               const unsigned short* __restrict__ Wp,
                                               const float* __restrict__ bias,
                                               const float* __restrict__ out_norm,
                                               float* __restrict__ z_out,
                                               unsigned short* __restrict__ zs) {
    __shared__ __align__(16) unsigned short lds[16 * 128 * 8];   // 32 KB packed W1
    {
        const uint4* s4 = (const uint4*)Wp; uint4* d4 = (uint4*)lds;
        for (int i = threadIdx.x; i < 2048; i += 256) d4[i] = s4[i];
    }
    __syncthreads();
    int wave = threadIdx.x >> 6, lane = threadIdx.x & 63;
    int base = (blockIdx.x * 4 + wave) * 16;
    if (base >= N_NODES) return;
    int m = lane & 15, q = lane >> 4;
    short8 a[4];
#pragma unroll
    for (int t = 0; t < 4; t++) a[t] = *(const short8*)(Ab + (size_t)(base + m) * 128 + t * 32 + q * 8);
    f32x4 acc[8];
#pragma unroll
    for (int c = 0; c < 8; c++) acc[c] = (f32x4)(0.f);
#pragma unroll
    for (int ct = 0; ct < 8; ct++) {
#pragma unroll
        for (int t = 0; t < 4; t++) {
            short8 b = *(const short8*)(lds + ((t * 4 + q) * 128 + ct * 16 + m) * 8);
            acc[ct] = __builtin_amdgcn_mfma_f32_16x16x32_bf16(a[t], b, acc[ct], 0, 0, 0);
        }
    }
    float onr[4];
#pragma unroll
    for (int i = 0; i < 4; i++) onr[i] = out_norm[base + q * 4 + i];
#pragma unroll
    for (int ct = 0; ct < 8; ct++) {
        int col = ct * 16 + m;
        float bv = bias[col];
#pragma unroll
        for (int i = 0; i < 4; i++) {
            int row = base + q * 4 + i;
            float v = acc[ct][i] + bv;
            v = v > 0.f ? v : 0.f;
            z_out[(size_t)row * 128 + col] = v;
            zs[(size_t)row * 128 + col] = f2bf(v * onr[i]);
        }
    }
}

// ---- GEMM2: tb = bf16(zs @ W2)  (N x 64 bf16 out; halves agg2 gather traffic) ----
__global__ __launch_bounds__(256) void k_gemm2(const unsigned short* __restrict__ Ab,
                                               const unsigned short* __restrict__ Wp,
                                               unsigned short* __restrict__ tb) {
    __shared__ __align__(16) unsigned short lds[16 * 64 * 8];   // 16 KB packed W2
    {
        const uint4* s4 = (const uint4*)Wp; uint4* d4 = (uint4*)lds;
        for (int i = threadIdx.x; i < 1024; i += 256) d4[i] = s4[i];
    }
    __syncthreads();
    int wave = threadIdx.x >> 6, lane = threadIdx.x & 63;
    int base = (blockIdx.x * 4 + wave) * 16;
    if (base >= N_NODES) return;
    int m = lane & 15, q = lane >> 4;
    short8 a[4];
#pragma unroll
    for (int t = 0; t < 4; t++) a[t] = *(const short8*)(Ab + (size_t)(base + m) * 128 + t * 32 + q * 8);
    f32x4 acc[4];
#pragma unroll
    for (int c = 0; c < 4; c++) acc[c] = (f32x4)(0.f);
#pragma unroll
    for (int ct = 0; ct < 4; ct++) {
#pragma unroll
        for (int t = 0; t < 4; t++) {
            short8 b = *(const short8*)(lds + ((t * 4 + q) * 64 + ct * 16 + m) * 8);
            acc[ct] = __builtin_amdgcn_mfma_f32_16x16x32_bf16(a[t], b, acc[ct], 0, 0, 0);
        }
    }
#pragma unroll
    for (int ct = 0; ct < 4; ct++) {
        int col = ct * 16 + m;
#pragma unroll
        for (int i = 0; i < 4; i++) {
            int row = base + q * 4 + i;
            tb[(size_t)row * 64 + col] = f2bf(acc[ct][i]);
        }
    }
}

// ---- layer-2 aggregation: wave per dst node, 64 bf16 cols (1/lane), f32 accum ----
// 8-deep unroll; 128 B contiguous per edge-instruction.
__global__ __launch_bounds__(256) void k_agg2(const unsigned short* __restrict__ tb,
                                              const int* __restrict__ row_ptr, const int* __restrict__ csr,
                                              const float* __restrict__ in_norm, const float* __restrict__ b2,
                                              float* __restrict__ out_h2) {
    int wave = threadIdx.x >> 6, lane = threadIdx.x & 63;
    int d = blockIdx.x * 4 + wave;
    if (d >= N_NODES) return;
    int e0 = __builtin_amdgcn_readfirstlane(row_ptr[d]);
    int e1 = __builtin_amdgcn_readfirstlane(row_ptr[d + 1]);
    float acc[8];
#pragma unroll
    for (int j = 0; j < 8; j++) acc[j] = 0.f;
    int e = e0;
    for (; e + 8 <= e1; e += 8) {
        int sI[8];
#pragma unroll
        for (int j = 0; j < 8; j++) sI[j] = __builtin_amdgcn_readfirstlane(csr[e + j]);
        unsigned short v[8];
#pragma unroll
        for (int j = 0; j < 8; j++) v[j] = tb[(size_t)sI[j] * 64 + lane];
#pragma unroll
        for (int j = 0; j < 8; j++) acc[j] += bf2f(v[j]);
    }
    for (; e < e1; e++) {
        int s = __builtin_amdgcn_readfirstlane(csr[e]);
        acc[0] += bf2f(tb[(size_t)s * 64 + lane]);
    }
    float a = 0.f;
#pragma unroll
    for (int j = 0; j < 8; j++) a += acc[j];
    out_h2[(size_t)d * 64 + lane] = a * in_norm[d] + b2[lane];
}

extern "C" void kernel_launch(void* const* d_in, const int* in_sizes, int n_in,
                              void* d_out, int out_size, void* d_ws, size_t ws_size,
                              hipStream_t stream) {
    const float* x   = (const float*)d_in[0];
    const int*   src = (const int*)d_in[1];
    const int*   dst = (const int*)d_in[2];
    const float* W1  = (const float*)d_in[3];
    const float* b1  = (const float*)d_in[4];
    const float* W2  = (const float*)d_in[5];
    const float* b2  = (const float*)d_in[6];
    float* out_h2 = (float*)d_out;                     // [N,64]
    float* out_z  = (float*)d_out + N_NODES * 64;      // [N,128]

    char* ws = (char*)d_ws;
    size_t off = 0;
    auto alloc = [&](size_t bytes) -> char* {
        char* p = ws + off;
        off = (off + bytes + 255) & ~(size_t)255;
        return p;
    };
    int* gcurD    = (int*)alloc(NB * 4);
    int* gcurS    = (int*)alloc(NB * 4);
    int* bbase    = (int*)alloc((NB + 1) * 4);
    int* row_ptr  = (int*)alloc((N_NODES + 1) * 4);
    float* out_norm = (float*)alloc(N_NODES * 4);
    float* in_norm  = (float*)alloc(N_NODES * 4);
    unsigned int* ebuf = (unsigned int*)alloc((size_t)NB * BCAP * 4);        // 8.0 MB
    unsigned char* ebufS = (unsigned char*)alloc((size_t)NB * BCAP);         // 2.0 MB
    int* csr_src  = (int*)alloc((size_t)N_EDGES * 4);
    unsigned short* Wp1 = (unsigned short*)alloc(2048 * 8 * 2);
    unsigned short* Wp2 = (unsigned short*)alloc(1024 * 8 * 2);
    unsigned short* xb    = (unsigned short*)alloc((size_t)N_NODES * 128 * 2);
    unsigned short* agg1b = (unsigned short*)alloc((size_t)N_NODES * 128 * 2);
    unsigned short* zs    = (unsigned short*)alloc((size_t)N_NODES * 128 * 2);
    unsigned short* tb    = (unsigned short*)alloc((size_t)N_NODES * 64 * 2);  // bf16 t
    (void)ws_size; (void)in_sizes; (void)n_in; (void)out_size;

    hipMemsetAsync(gcurD, 0, NB * 4, stream);
    hipMemsetAsync(gcurS, 0, NB * 4, stream);

    const int GD_AGG = (N_NODES + 3) / 4;       // 25000
    const int GD_GEMM = (N_NODES / 16 + 3) / 4; // 1563

    k_part<<<PART_BLOCKS, 256, 0, stream>>>(src, dst, gcurD, gcurS, ebuf, ebufS);
    k_bhist<<<NB, 256, 0, stream>>>(ebufS, gcurS, out_norm);
    k_bscan<<<1, 512, 0, stream>>>(gcurD, bbase, row_ptr);
    k_bsort<<<NB, 256, 0, stream>>>(ebuf, gcurD, bbase, csr_src, row_ptr, in_norm);
    k_xb<<<N_NODES * 32 / 256, 256, 0, stream>>>(x, out_norm, xb);
    k_pack_w<<<12, 256, 0, stream>>>(W1, W2, Wp1, Wp2);
    k_agg1<<<GD_AGG, 256, 0, stream>>>(xb, row_ptr, csr_src, in_norm, agg1b);
    k_gemm1<<<GD_GEMM, 256, 0, stream>>>(agg1b, Wp1, b1, out_norm, out_z, zs);
    k_gemm2<<<GD_GEMM, 256, 0, stream>>>(zs, Wp2, tb);
    k_agg2<<<GD_AGG, 256, 0, stream>>>(tb, row_ptr, csr_src, in_norm, b2, out_h2);
}

// Round 7
// 327.182 us; speedup vs baseline: 1.7660x; 1.0320x over previous
//
#include <hip/hip_runtime.h>

#define N_NODES 100000
#define N_EDGES 1600000
#define NB 391          // coarse buckets of 256 nodes
#define BCAP 5120       // per-bucket capacity (expected 4096, 16-sigma headroom)
#define PART_BLOCKS 250
#define EPB 6400        // edges per partition block (250*6400 = 1.6M exact)

typedef __attribute__((ext_vector_type(8))) short short8;   // 8 bf16 (4 VGPR) MFMA frag
typedef __attribute__((ext_vector_type(4))) float f32x4;    // MFMA accumulator

__device__ inline unsigned short f2bf(float f) {
    unsigned int u = __builtin_bit_cast(unsigned int, f);
    u += 0x7fffu + ((u >> 16) & 1u);   // round-to-nearest-even
    return (unsigned short)(u >> 16);
}
__device__ inline float bf2f(unsigned short h) {
    unsigned int u = ((unsigned int)h) << 16;
    return __builtin_bit_cast(float, u);
}

// ---- xb = bf16(x * out_norm[row]) ----
__global__ __launch_bounds__(256) void k_xb(const float* __restrict__ x, const float* __restrict__ out_norm,
                                            unsigned short* __restrict__ xb) {
    int tid = blockIdx.x * 256 + threadIdx.x;   // grid exactly N*32
    int row = tid >> 5;
    float4 v = ((const float4*)x)[tid];
    float w = out_norm[row];
    unsigned int lo = (unsigned int)f2bf(v.x * w) | ((unsigned int)f2bf(v.y * w) << 16);
    unsigned int hi = (unsigned int)f2bf(v.z * w) | ((unsigned int)f2bf(v.w * w) << 16);
    ((uint2*)xb)[tid] = make_uint2(lo, hi);
}

// ---- pack W1/W2 (f32) into bf16 B-fragment layout: entry (kq, c) = W[kq*8+j][c], j=0..7 ----
__global__ __launch_bounds__(256) void k_pack_w(const float* __restrict__ W1, const float* __restrict__ W2,
                                                unsigned short* __restrict__ Wp1, unsigned short* __restrict__ Wp2) {
    int i = blockIdx.x * 256 + threadIdx.x;   // 3072 total
    if (i < 2048) {                           // W1: 16 kq x 128 c
        int kq = i >> 7, c = i & 127;
#pragma unroll
        for (int j = 0; j < 8; j++) Wp1[i * 8 + j] = f2bf(W1[(kq * 8 + j) * 128 + c]);
    } else if (i < 3072) {                    // W2: 16 kq x 64 c
        int i2 = i - 2048;
        int kq = i2 >> 6, c = i2 & 63;
#pragma unroll
        for (int j = 0; j < 8; j++) Wp2[i2 * 8 + j] = f2bf(W2[(kq * 8 + j) * 64 + c]);
    }
}

// ---- partition: dst-keyed buckets (full edge) + src-keyed buckets (1 byte) ----
__global__ __launch_bounds__(256) void k_part(const int* __restrict__ src, const int* __restrict__ dst,
                                              int* __restrict__ gcurD, int* __restrict__ gcurS,
                                              unsigned int* __restrict__ ebuf,
                                              unsigned char* __restrict__ ebufS) {
    __shared__ int histD[NB], gbaseD[NB];
    __shared__ int histS[NB], gbaseS[NB];
    for (int i = threadIdx.x; i < NB; i += 256) { histD[i] = 0; histS[i] = 0; }
    __syncthreads();
    int base = blockIdx.x * EPB;
    for (int i = threadIdx.x; i < EPB; i += 256) {
        int d = dst[base + i], s = src[base + i];
        atomicAdd(&histD[d >> 8], 1);
        atomicAdd(&histS[s >> 8], 1);
    }
    __syncthreads();
    for (int i = threadIdx.x; i < NB; i += 256) {
        gbaseD[i] = atomicAdd(&gcurD[i], histD[i]);
        gbaseS[i] = atomicAdd(&gcurS[i], histS[i]);
        histD[i] = 0;                          // reuse as local run cursors
        histS[i] = 0;
    }
    __syncthreads();
    for (int i = threadIdx.x; i < EPB; i += 256) {
        int d = dst[base + i], s = src[base + i];
        int bd = d >> 8;
        int r = atomicAdd(&histD[bd], 1);
        int pos = gbaseD[bd] + r;
        if (pos < BCAP) ebuf[(size_t)bd * BCAP + pos] = ((unsigned int)s << 8) | (unsigned int)(d & 255);
        int bs = s >> 8;
        int r2 = atomicAdd(&histS[bs], 1);
        int pos2 = gbaseS[bs] + r2;
        if (pos2 < BCAP) ebufS[(size_t)bs * BCAP + pos2] = (unsigned char)(s & 255);
    }
}

// ---- per-bucket out-degree histogram -> out_norm ----
__global__ __launch_bounds__(256) void k_bhist(const unsigned char* __restrict__ ebufS,
                                               const int* __restrict__ gcurS,
                                               float* __restrict__ out_norm) {
    __shared__ int hist[256];
    int b = blockIdx.x, t = threadIdx.x;
    hist[t] = 0;
    __syncthreads();
    int ne = min(gcurS[b], BCAP);
    const unsigned char* eb = ebufS + (size_t)b * BCAP;
    for (int i = t; i < ne; i += 256) atomicAdd(&hist[eb[i]], 1);
    __syncthreads();
    int node = b * 256 + t;
    if (node < N_NODES) out_norm[node] = hist[t] > 0 ? rsqrtf((float)hist[t]) : 1.0f;
}

// ---- exclusive scan of dst-bucket counts -> bucket bases; row_ptr[N] = E ----
__global__ __launch_bounds__(512) void k_bscan(const int* __restrict__ gcurD, int* __restrict__ bbase,
                                               int* __restrict__ row_ptr) {
    __shared__ int s[NB + 1];
    int t = threadIdx.x;
    if (t < NB) s[t] = min(gcurD[t], BCAP);
    __syncthreads();
    if (t == 0) {
        int run = 0;
        for (int b = 0; b < NB; b++) { int v = s[b]; s[b] = run; run += v; }
        s[NB] = run;
    }
    __syncthreads();
    if (t < NB) bbase[t] = s[t];
    if (t == 0) { bbase[NB] = s[NB]; row_ptr[N_NODES] = s[NB]; }
}

// ---- per-bucket counting sort in LDS: emits coalesced csr_src, row_ptr, in_norm ----
__global__ __launch_bounds__(256) void k_bsort(const unsigned int* __restrict__ ebuf, const int* __restrict__ gcurD,
                                               const int* __restrict__ bbase, int* __restrict__ csr_src,
                                               int* __restrict__ row_ptr, float* __restrict__ in_norm) {
    __shared__ unsigned int st[BCAP];   // 20 KB staged edges
    __shared__ int perm[BCAP];          // 20 KB sorted srcs
    __shared__ int hist[256], cursor[256], sa[256], sb[256];
    int b = blockIdx.x, t = threadIdx.x;
    int ne = min(gcurD[b], BCAP);
    const unsigned int* eb = ebuf + (size_t)b * BCAP;
    hist[t] = 0;
    __syncthreads();
    for (int i = t; i < ne; i += 256) {
        unsigned int pk = eb[i];
        st[i] = pk;
        atomicAdd(&hist[pk & 255u], 1);
    }
    __syncthreads();
    sa[t] = hist[t];
    __syncthreads();
    int* cur = sa; int* nxt = sb;
    for (int o = 1; o < 256; o <<= 1) {
        int v = cur[t] + (t >= o ? cur[t - o] : 0);
        nxt[t] = v;
        __syncthreads();
        int* tmp = cur; cur = nxt; nxt = tmp;
    }
    int ex = cur[t] - hist[t];   // exclusive
    cursor[t] = ex;
    int node = b * 256 + t;
    if (node < N_NODES) {
        row_ptr[node] = bbase[b] + ex;
        in_norm[node] = hist[t] > 0 ? rsqrtf((float)hist[t]) : 1.0f;
    }
    __syncthreads();
    for (int i = t; i < ne; i += 256) {
        unsigned int pk = st[i];
        int pos = atomicAdd(&cursor[pk & 255u], 1);
        perm[pos] = (int)(pk >> 8);
    }
    __syncthreads();
    int gb = bbase[b];
    for (int i = t; i < ne; i += 256) csr_src[gb + i] = perm[i];
}

// ---- layer-1 aggregation: wave per dst node, 128 bf16 cols (2/lane), f32 accum ----
// 16-deep unrolled gather (R6: 8-deep left VALUBusy 33%, HBM 56% of achievable
// -> still latency-bound). 256 B contiguous per edge-instruction (R5 lesson).
__global__ __launch_bounds__(256) void k_agg1(const unsigned short* __restrict__ xb,
                                              const int* __restrict__ row_ptr, const int* __restrict__ csr,
                                              const float* __restrict__ in_norm,
                                              unsigned short* __restrict__ aggb) {
    int wave = threadIdx.x >> 6, lane = threadIdx.x & 63;
    int d = blockIdx.x * 4 + wave;
    if (d >= N_NODES) return;
    int e0 = __builtin_amdgcn_readfirstlane(row_ptr[d]);
    int e1 = __builtin_amdgcn_readfirstlane(row_ptr[d + 1]);
    int col = lane << 1;
    float accL[8], accH[8];
#pragma unroll
    for (int j = 0; j < 8; j++) { accL[j] = 0.f; accH[j] = 0.f; }
    int e = e0;
    for (; e + 16 <= e1; e += 16) {
        int sI[16];
#pragma unroll
        for (int j = 0; j < 16; j++) sI[j] = __builtin_amdgcn_readfirstlane(csr[e + j]);
        unsigned int v[16];
#pragma unroll
        for (int j = 0; j < 16; j++) v[j] = *(const unsigned int*)(xb + (size_t)sI[j] * 128 + col);
#pragma unroll
        for (int j = 0; j < 16; j++) {
            accL[j & 7] += bf2f((unsigned short)(v[j] & 0xffffu));
            accH[j & 7] += bf2f((unsigned short)(v[j] >> 16));
        }
    }
    for (; e + 8 <= e1; e += 8) {
        int sI[8];
#pragma unroll
        for (int j = 0; j < 8; j++) sI[j] = __builtin_amdgcn_readfirstlane(csr[e + j]);
        unsigned int v[8];
#pragma unroll
        for (int j = 0; j < 8; j++) v[j] = *(const unsigned int*)(xb + (size_t)sI[j] * 128 + col);
#pragma unroll
        for (int j = 0; j < 8; j++) {
            accL[j] += bf2f((unsigned short)(v[j] & 0xffffu));
            accH[j] += bf2f((unsigned short)(v[j] >> 16));
        }
    }
    for (; e < e1; e++) {
        int s = __builtin_amdgcn_readfirstlane(csr[e]);
        unsigned int v = *(const unsigned int*)(xb + (size_t)s * 128 + col);
        accL[0] += bf2f((unsigned short)(v & 0xffffu));
        accH[0] += bf2f((unsigned short)(v >> 16));
    }
    float a0 = 0.f, a1 = 0.f;
#pragma unroll
    for (int j = 0; j < 8; j++) { a0 += accL[j]; a1 += accH[j]; }
    float w = in_norm[d];
    unsigned int pk = (unsigned int)f2bf(a0 * w) | ((unsigned int)f2bf(a1 * w) << 16);
    *(unsigned int*)(aggb + (size_t)d * 128 + col) = pk;
}

// ---- fused GEMM1+GEMM2: z = relu(agg1b@W1+b1) -> z_out; zs=bf16(z*out_norm)
// round-trips through a wave-private LDS tile (stride 132 ushorts: conflict-free
// for both the C-layout store and the A-layout ds_read_b128); tb = bf16(zs@W2).
// Saves the 25.6 MB zs write + 25.6 MB read of the split version.
__global__ __launch_bounds__(256) void k_gemm12(const unsigned short* __restrict__ Ab,
                                                const unsigned short* __restrict__ Wp1,
                                                const unsigned short* __restrict__ Wp2,
                                                const float* __restrict__ bias1,
                                                const float* __restrict__ out_norm,
                                                float* __restrict__ z_out,
                                                unsigned short* __restrict__ tb) {
    __shared__ __align__(16) unsigned short lds1[16 * 128 * 8];   // 32 KB packed W1
    __shared__ __align__(16) unsigned short lds2[16 * 64 * 8];    // 16 KB packed W2
    __shared__ __align__(16) unsigned short zt[64 * 132];         // 16.5 KB zs tile
    {
        const uint4* s1 = (const uint4*)Wp1; uint4* d1 = (uint4*)lds1;
        for (int i = threadIdx.x; i < 2048; i += 256) d1[i] = s1[i];
        const uint4* s2 = (const uint4*)Wp2; uint4* d2 = (uint4*)lds2;
        for (int i = threadIdx.x; i < 1024; i += 256) d2[i] = s2[i];
    }
    __syncthreads();   // the only barrier; inactive waves may return after it
    int wave = threadIdx.x >> 6, lane = threadIdx.x & 63;
    int base = (blockIdx.x * 4 + wave) * 16;
    if (base >= N_NODES) return;
    int m = lane & 15, q = lane >> 4;
    // ---- GEMM1 ----
    short8 a[4];
#pragma unroll
    for (int t = 0; t < 4; t++) a[t] = *(const short8*)(Ab + (size_t)(base + m) * 128 + t * 32 + q * 8);
    f32x4 acc[8];
#pragma unroll
    for (int c = 0; c < 8; c++) acc[c] = (f32x4)(0.f);
#pragma unroll
    for (int ct = 0; ct < 8; ct++) {
#pragma unroll
        for (int t = 0; t < 4; t++) {
            short8 b = *(const short8*)(lds1 + ((t * 4 + q) * 128 + ct * 16 + m) * 8);
            acc[ct] = __builtin_amdgcn_mfma_f32_16x16x32_bf16(a[t], b, acc[ct], 0, 0, 0);
        }
    }
    float onr[4];
#pragma unroll
    for (int i = 0; i < 4; i++) onr[i] = out_norm[base + q * 4 + i];
#pragma unroll
    for (int ct = 0; ct < 8; ct++) {
        int col = ct * 16 + m;
        float bv = bias1[col];
#pragma unroll
        for (int i = 0; i < 4; i++) {
            int row = base + q * 4 + i;
            float v = acc[ct][i] + bv;
            v = v > 0.f ? v : 0.f;
            z_out[(size_t)row * 128 + col] = v;
            zt[(wave * 16 + q * 4 + i) * 132 + col] = f2bf(v * onr[i]);
        }
    }
    // zt rows are wave-private (wave w writes & reads rows w*16..w*16+15);
    // intra-wave LDS dependency -> compiler's lgkmcnt suffices, no barrier.
    // ---- GEMM2 ----
    short8 a2[4];
#pragma unroll
    for (int t = 0; t < 4; t++) a2[t] = *(const short8*)(zt + (wave * 16 + m) * 132 + t * 32 + q * 8);
    f32x4 acc2[4];
#pragma unroll
    for (int c = 0; c < 4; c++) acc2[c] = (f32x4)(0.f);
#pragma unroll
    for (int ct = 0; ct < 4; ct++) {
#pragma unroll
        for (int t = 0; t < 4; t++) {
            short8 b = *(const short8*)(lds2 + ((t * 4 + q) * 64 + ct * 16 + m) * 8);
            acc2[ct] = __builtin_amdgcn_mfma_f32_16x16x32_bf16(a2[t], b, acc2[ct], 0, 0, 0);
        }
    }
#pragma unroll
    for (int ct = 0; ct < 4; ct++) {
        int col = ct * 16 + m;
#pragma unroll
        for (int i = 0; i < 4; i++) {
            int row = base + q * 4 + i;
            tb[(size_t)row * 64 + col] = f2bf(acc2[ct][i]);
        }
    }
}

// ---- layer-2 aggregation: wave per dst node, 64 bf16 cols (1/lane), f32 accum ----
// 16-deep unroll; 128 B contiguous per edge-instruction.
__global__ __launch_bounds__(256) void k_agg2(const unsigned short* __restrict__ tb,
                                              const int* __restrict__ row_ptr, const int* __restrict__ csr,
                                              const float* __restrict__ in_norm, const float* __restrict__ b2,
                                              float* __restrict__ out_h2) {
    int wave = threadIdx.x >> 6, lane = threadIdx.x & 63;
    int d = blockIdx.x * 4 + wave;
    if (d >= N_NODES) return;
    int e0 = __builtin_amdgcn_readfirstlane(row_ptr[d]);
    int e1 = __builtin_amdgcn_readfirstlane(row_ptr[d + 1]);
    float acc[8];
#pragma unroll
    for (int j = 0; j < 8; j++) acc[j] = 0.f;
    int e = e0;
    for (; e + 16 <= e1; e += 16) {
        int sI[16];
#pragma unroll
        for (int j = 0; j < 16; j++) sI[j] = __builtin_amdgcn_readfirstlane(csr[e + j]);
        unsigned short v[16];
#pragma unroll
        for (int j = 0; j < 16; j++) v[j] = tb[(size_t)sI[j] * 64 + lane];
#pragma unroll
        for (int j = 0; j < 16; j++) acc[j & 7] += bf2f(v[j]);
    }
    for (; e + 8 <= e1; e += 8) {
        int sI[8];
#pragma unroll
        for (int j = 0; j < 8; j++) sI[j] = __builtin_amdgcn_readfirstlane(csr[e + j]);
        unsigned short v[8];
#pragma unroll
        for (int j = 0; j < 8; j++) v[j] = tb[(size_t)sI[j] * 64 + lane];
#pragma unroll
        for (int j = 0; j < 8; j++) acc[j] += bf2f(v[j]);
    }
    for (; e < e1; e++) {
        int s = __builtin_amdgcn_readfirstlane(csr[e]);
        acc[0] += bf2f(tb[(size_t)s * 64 + lane]);
    }
    float a = 0.f;
#pragma unroll
    for (int j = 0; j < 8; j++) a += acc[j];
    out_h2[(size_t)d * 64 + lane] = a * in_norm[d] + b2[lane];
}

extern "C" void kernel_launch(void* const* d_in, const int* in_sizes, int n_in,
                              void* d_out, int out_size, void* d_ws, size_t ws_size,
                              hipStream_t stream) {
    const float* x   = (const float*)d_in[0];
    const int*   src = (const int*)d_in[1];
    const int*   dst = (const int*)d_in[2];
    const float* W1  = (const float*)d_in[3];
    const float* b1  = (const float*)d_in[4];
    const float* W2  = (const float*)d_in[5];
    const float* b2  = (const float*)d_in[6];
    float* out_h2 = (float*)d_out;                     // [N,64]
    float* out_z  = (float*)d_out + N_NODES * 64;      // [N,128]

    char* ws = (char*)d_ws;
    size_t off = 0;
    auto alloc = [&](size_t bytes) -> char* {
        char* p = ws + off;
        off = (off + bytes + 255) & ~(size_t)255;
        return p;
    };
    int* gcurD    = (int*)alloc(NB * 4);
    int* gcurS    = (int*)alloc(NB * 4);
    int* bbase    = (int*)alloc((NB + 1) * 4);
    int* row_ptr  = (int*)alloc((N_NODES + 1) * 4);
    float* out_norm = (float*)alloc(N_NODES * 4);
    float* in_norm  = (float*)alloc(N_NODES * 4);
    unsigned int* ebuf = (unsigned int*)alloc((size_t)NB * BCAP * 4);        // 8.0 MB
    unsigned char* ebufS = (unsigned char*)alloc((size_t)NB * BCAP);         // 2.0 MB
    int* csr_src  = (int*)alloc((size_t)N_EDGES * 4);
    unsigned short* Wp1 = (unsigned short*)alloc(2048 * 8 * 2);
    unsigned short* Wp2 = (unsigned short*)alloc(1024 * 8 * 2);
    unsigned short* xb    = (unsigned short*)alloc((size_t)N_NODES * 128 * 2);
    unsigned short* agg1b = (unsigned short*)alloc((size_t)N_NODES * 128 * 2);
    unsigned short* tb    = (unsigned short*)alloc((size_t)N_NODES * 64 * 2);  // bf16 t
    (void)ws_size; (void)in_sizes; (void)n_in; (void)out_size;

    hipMemsetAsync(gcurD, 0, NB * 4, stream);
    hipMemsetAsync(gcurS, 0, NB * 4, stream);

    const int GD_AGG = (N_NODES + 3) / 4;       // 25000
    const int GD_GEMM = (N_NODES / 16 + 3) / 4; // 1563

    k_part<<<PART_BLOCKS, 256, 0, stream>>>(src, dst, gcurD, gcurS, ebuf, ebufS);
    k_bhist<<<NB, 256, 0, stream>>>(ebufS, gcurS, out_norm);
    k_bscan<<<1, 512, 0, stream>>>(gcurD, bbase, row_ptr);
    k_bsort<<<NB, 256, 0, stream>>>(ebuf, gcurD, bbase, csr_src, row_ptr, in_norm);
    k_xb<<<N_NODES * 32 / 256, 256, 0, stream>>>(x, out_norm, xb);
    k_pack_w<<<12, 256, 0, stream>>>(W1, W2, Wp1, Wp2);
    k_agg1<<<GD_AGG, 256, 0, stream>>>(xb, row_ptr, csr_src, in_norm, agg1b);
    k_gemm12<<<GD_GEMM, 256, 0, stream>>>(agg1b, Wp1, Wp2, b1, out_norm, out_z, tb);
    k_agg2<<<GD_AGG, 256, 0, stream>>>(tb, row_ptr, csr_src, in_norm, b2, out_h2);
}